// Round 7
// baseline (401.052 us; speedup 1.0000x reference)
//
#include <hip/hip_runtime.h>
#include <hip/hip_bf16.h>

// Fused causal MHA for MI355X (gfx950).
// Round-7:
//  * attn: unpaired (1 q-tile/wave, 4096 waves = 4/SIMD), bh->XCD L2 locality,
//    K+V double-buffer register prefetch, setprio around MFMA.
//  * qkv GEMM back to 128x128 (768 blocks = 3/CU, m97 structure).
// Workspace (48 MB): [0,8M) x_bf16 | [8,16M) Wq/Wk/Wv/Wo bf16
//   [16,24M) Q (b,h,n,d) bf16 pre-scaled 0.125*log2e | [24,32M) K (b,h,n,d)
//   [32,40M) V^T (b,h,d,n) | [40,48M) attn_out (b,n,h*dv) bf16

using bf16x8   = __attribute__((ext_vector_type(8))) __bf16;
using f32x4    = __attribute__((ext_vector_type(4))) float;
using ushort4v = __attribute__((ext_vector_type(4))) unsigned short;

__device__ __forceinline__ unsigned short f2bf(float f) {
    unsigned int u = __float_as_uint(f);
    u += 0x7FFFu + ((u >> 16) & 1u);
    return (unsigned short)(u >> 16);
}

__device__ __forceinline__ unsigned cvtpk(float lo, float hi) {
    unsigned r;
    asm("v_cvt_pk_bf16_f32 %0, %1, %2" : "=v"(r) : "v"(lo), "v"(hi));
    return r;
}

__device__ __forceinline__ void gll16(const void* g, void* l) {
    __builtin_amdgcn_global_load_lds(
        (const __attribute__((address_space(1))) void*)g,
        (__attribute__((address_space(3))) void*)l, 16, 0, 0);
}

__global__ __launch_bounds__(256) void cast_bf16_kernel(
    const float* __restrict__ in, unsigned short* __restrict__ out, int n4) {
    int i = blockIdx.x * 256 + threadIdx.x;
    if (i >= n4) return;
    float4 f = reinterpret_cast<const float4*>(in)[i];
    ushort4v o;
    o.x = f2bf(f.x); o.y = f2bf(f.y); o.z = f2bf(f.z); o.w = f2bf(f.w);
    reinterpret_cast<ushort4v*>(out)[i] = o;
}

__global__ __launch_bounds__(256) void cast_w4_kernel(
    const float* __restrict__ w0, const float* __restrict__ w1,
    const float* __restrict__ w2, const float* __restrict__ w3,
    unsigned short* __restrict__ o0, unsigned short* __restrict__ o1,
    unsigned short* __restrict__ o2, unsigned short* __restrict__ o3) {
    const int z = blockIdx.y;
    const float* in = (z == 0) ? w0 : (z == 1) ? w1 : (z == 2) ? w2 : w3;
    unsigned short* out = (z == 0) ? o0 : (z == 1) ? o1 : (z == 2) ? o2 : o3;
    int i = blockIdx.x * 256 + threadIdx.x;
    float4 f = reinterpret_cast<const float4*>(in)[i];
    ushort4v o;
    o.x = f2bf(f.x); o.y = f2bf(f.y); o.z = f2bf(f.z); o.w = f2bf(f.w);
    reinterpret_cast<ushort4v*>(out)[i] = o;
}

// ---- 128x128 GEMM core (m97 structure): C = A(MxK) * B(NxK)^T ----
// LDS linear [128][32] bf16 per operand; 4 waves 2x2; 4x4 frags/wave.
__device__ __forceinline__ void gemm_core_128(
    const unsigned short* __restrict__ A, const unsigned short* __restrict__ B,
    int m0, int n0, int K,
    unsigned short* As, unsigned short* Bs, f32x4 acc[4][4]) {
    const int tid = threadIdx.x;
    const int lane = tid & 63;
    const int wid = tid >> 6;
    const int wr = wid >> 1, wc = wid & 1;
    const int l16 = lane & 15, lg = lane >> 4;

#pragma unroll
    for (int i = 0; i < 4; i++)
#pragma unroll
        for (int j = 0; j < 4; j++) acc[i][j] = f32x4{0.f, 0.f, 0.f, 0.f};

    const int srow = lane >> 2;
    const int scol = (lane & 3) * 8;
    const unsigned short* Ab0 = &A[(size_t)(m0 + wid * 16 + srow) * K + scol];
    const unsigned short* Ab1 = &A[(size_t)(m0 + 64 + wid * 16 + srow) * K + scol];
    const unsigned short* Bb0 = &B[(size_t)(n0 + wid * 16 + srow) * K + scol];
    const unsigned short* Bb1 = &B[(size_t)(n0 + 64 + wid * 16 + srow) * K + scol];
    unsigned short* AsW0 = As + (wid * 16) * 32;
    unsigned short* AsW1 = As + (64 + wid * 16) * 32;
    unsigned short* BsW0 = Bs + (wid * 16) * 32;
    unsigned short* BsW1 = Bs + (64 + wid * 16) * 32;

    for (int k0 = 0; k0 < K; k0 += 32) {
        __syncthreads();
        gll16(Ab0 + k0, AsW0);
        gll16(Ab1 + k0, AsW1);
        gll16(Bb0 + k0, BsW0);
        gll16(Bb1 + k0, BsW1);
        __syncthreads();
        bf16x8 af[4], bfr[4];
#pragma unroll
        for (int i = 0; i < 4; i++)
            af[i] = *reinterpret_cast<const bf16x8*>(&As[(64 * wr + 16 * i + l16) * 32 + 8 * lg]);
#pragma unroll
        for (int j = 0; j < 4; j++)
            bfr[j] = *reinterpret_cast<const bf16x8*>(&Bs[(64 * wc + 16 * j + l16) * 32 + 8 * lg]);
#pragma unroll
        for (int i = 0; i < 4; i++)
#pragma unroll
            for (int j = 0; j < 4; j++)
                acc[i][j] = __builtin_amdgcn_mfma_f32_16x16x32_bf16(af[i], bfr[j], acc[i][j], 0, 0, 0);
    }
}

// ---- 128x64 GEMM core (for out-proj: N=1024 -> 512 blocks = 2/CU) ----
__device__ __forceinline__ void gemm_core_128x64(
    const unsigned short* __restrict__ A, const unsigned short* __restrict__ B,
    int m0, int n0, int K,
    unsigned short* As, unsigned short* Bs, f32x4 acc[4][2]) {
    const int tid = threadIdx.x;
    const int lane = tid & 63;
    const int wid = tid >> 6;
    const int wr = wid >> 1, wc = wid & 1;
    const int l16 = lane & 15, lg = lane >> 4;

#pragma unroll
    for (int i = 0; i < 4; i++)
#pragma unroll
        for (int j = 0; j < 2; j++) acc[i][j] = f32x4{0.f, 0.f, 0.f, 0.f};

    const int srow = lane >> 2;
    const int scol = (lane & 3) * 8;
    const unsigned short* Ab0 = &A[(size_t)(m0 + wid * 16 + srow) * K + scol];
    const unsigned short* Ab1 = &A[(size_t)(m0 + 64 + wid * 16 + srow) * K + scol];
    const unsigned short* Bb0 = &B[(size_t)(n0 + wid * 16 + srow) * K + scol];
    unsigned short* AsW0 = As + (wid * 16) * 32;
    unsigned short* AsW1 = As + (64 + wid * 16) * 32;
    unsigned short* BsW0 = Bs + (wid * 16) * 32;

    for (int k0 = 0; k0 < K; k0 += 32) {
        __syncthreads();
        gll16(Ab0 + k0, AsW0);
        gll16(Ab1 + k0, AsW1);
        gll16(Bb0 + k0, BsW0);
        __syncthreads();
        bf16x8 af[4], bfr[2];
#pragma unroll
        for (int i = 0; i < 4; i++)
            af[i] = *reinterpret_cast<const bf16x8*>(&As[(64 * wr + 16 * i + l16) * 32 + 8 * lg]);
#pragma unroll
        for (int j = 0; j < 2; j++)
            bfr[j] = *reinterpret_cast<const bf16x8*>(&Bs[(32 * wc + 16 * j + l16) * 32 + 8 * lg]);
#pragma unroll
        for (int i = 0; i < 4; i++)
#pragma unroll
            for (int j = 0; j < 2; j++)
                acc[i][j] = __builtin_amdgcn_mfma_f32_16x16x32_bf16(af[i], bfr[j], acc[i][j], 0, 0, 0);
    }
}

// ---- QKV projection: z=0 -> Q (scaled 0.125*log2e), z=1 -> K, z=2 -> V^T ----
__global__ __launch_bounds__(256) void gemm_qkv_kernel(
    const unsigned short* __restrict__ xbf,
    const unsigned short* __restrict__ wq, const unsigned short* __restrict__ wk,
    const unsigned short* __restrict__ wv,
    const float* __restrict__ bq, const float* __restrict__ bk, const float* __restrict__ bv,
    unsigned short* __restrict__ q_ws, unsigned short* __restrict__ k_ws,
    unsigned short* __restrict__ vt_ws) {
    __shared__ __align__(16) unsigned short As[128 * 32];
    __shared__ __align__(16) unsigned short Bs[128 * 32];
    const int z = blockIdx.z;
    const unsigned short* W = (z == 0) ? wq : ((z == 1) ? wk : wv);
    const float* bias = (z == 0) ? bq : ((z == 1) ? bk : bv);
    const float scale = (z == 0) ? 0.125f * 1.44269504f : 1.0f;
    const int m0 = blockIdx.y * 128;
    const int n0 = blockIdx.x * 128;

    f32x4 acc[4][4];
    gemm_core_128(xbf, W, m0, n0, 1024, As, Bs, acc);

    const int tid = threadIdx.x;
    const int lane = tid & 63;
    const int wid = tid >> 6;
    const int wr = wid >> 1, wc = wid & 1;
    const int l16 = lane & 15, lg = lane >> 4;

#pragma unroll
    for (int j = 0; j < 4; j++) {
        const int c = n0 + 64 * wc + 16 * j + l16;
        const float bc = bias[c];
        const int h = c >> 6, d = c & 63;
#pragma unroll
        for (int i = 0; i < 4; i++) {
            const int mb = m0 + 64 * wr + 16 * i + 4 * lg;
            if (z < 2) {
                unsigned short* dst = (z == 0) ? q_ws : k_ws;
#pragma unroll
                for (int r = 0; r < 4; r++) {
                    int m = mb + r;
                    int b = m >> 11, n = m & 2047;
                    float v = (acc[i][j][r] + bc) * scale;
                    dst[(((b * 16 + h) * 2048 + n) << 6) + d] = f2bf(v);
                }
            } else {
                int b = mb >> 11, n = mb & 2047;
                ushort4v pk;
                pk.x = f2bf(acc[i][j][0] + bc);
                pk.y = f2bf(acc[i][j][1] + bc);
                pk.z = f2bf(acc[i][j][2] + bc);
                pk.w = f2bf(acc[i][j][3] + bc);
                *reinterpret_cast<ushort4v*>(&vt_ws[((b * 16 + h) * 64 + d) * 2048 + n]) = pk;
            }
        }
    }
}

// ---- Flash attention v4: unpaired, 4 waves/SIMD, K+V dbuf, setprio ----
// bid: xcd = bid&7, idx = bid>>3; bh = xcd*4 + idx/32 (XCD-local K/V in L2);
// wave q-tile t = (idx%32)*4 + wid; 16 q-rows; KV tiles of 32.
__global__ __launch_bounds__(256, 4) void attn_kernel(
    const unsigned short* __restrict__ q_ws, const unsigned short* __restrict__ k_ws,
    const unsigned short* __restrict__ vt_ws, unsigned short* __restrict__ attn_out) {
    __shared__ __align__(16) unsigned short P_lds[4][16][40];   // per-wave
    const int tid = threadIdx.x;
    const int wid = tid >> 6, lane = tid & 63;
    const int l16 = lane & 15, lg = lane >> 4;
    const int bid = blockIdx.x;              // 0..1023
    const int xcd = bid & 7, idx = bid >> 3; // idx 0..127
    const int bh = xcd * 4 + (idx >> 5);     // 0..31
    const int t = ((idx & 31) << 2) + wid;   // 0..127, lengths mixed per wid
    const int q0 = t << 4;
    const unsigned short* qb = q_ws + bh * (2048 * 64);
    const unsigned short* kb = k_ws + bh * (2048 * 64);
    const unsigned short* vb = vt_ws + bh * (64 * 2048);

    bf16x8 aq0 = *reinterpret_cast<const bf16x8*>(&qb[(q0 + l16) * 64 + 8 * lg]);
    bf16x8 aq1 = *reinterpret_cast<const bf16x8*>(&qb[(q0 + l16) * 64 + 32 + 8 * lg]);

    f32x4 o[4];
#pragma unroll
    for (int j = 0; j < 4; j++) o[j] = f32x4{0.f, 0.f, 0.f, 0.f};
    float mX = -1e30f, lX = 0.f;

    const int kvEnd = q0 + 16;

    // softmax (log2 domain) + PV for one KV tile, K/V passed in registers
    auto process = [&](const bf16x8& c00, const bf16x8& c01,
                       const bf16x8& c10, const bf16x8& c11,
                       const bf16x8& w0, const bf16x8& w1,
                       const bf16x8& w2, const bf16x8& w3,
                       int kv0, bool diag) {
        const f32x4 zz = f32x4{0.f, 0.f, 0.f, 0.f};
        __builtin_amdgcn_s_setprio(1);
        f32x4 s0 = __builtin_amdgcn_mfma_f32_16x16x32_bf16(c00, aq0, zz, 0, 0, 0);
        s0 = __builtin_amdgcn_mfma_f32_16x16x32_bf16(c01, aq1, s0, 0, 0, 0);
        f32x4 s1 = __builtin_amdgcn_mfma_f32_16x16x32_bf16(c10, aq0, zz, 0, 0, 0);
        s1 = __builtin_amdgcn_mfma_f32_16x16x32_bf16(c11, aq1, s1, 0, 0, 0);
        __builtin_amdgcn_s_setprio(0);
        if (diag) {
            const int kbase = kv0 + 4 * lg;
            const int qrow = q0 + l16;
#pragma unroll
            for (int r = 0; r < 4; r++) {
                if (kbase + r > qrow) s0[r] = -1e30f;
                if (kbase + 16 + r > qrow) s1[r] = -1e30f;
            }
        }
        float mx = fmaxf(fmaxf(fmaxf(s0[0], s0[1]), fmaxf(s0[2], s0[3])),
                         fmaxf(fmaxf(s1[0], s1[1]), fmaxf(s1[2], s1[3])));
        mx = fmaxf(mx, __shfl_xor(mx, 16));
        mx = fmaxf(mx, __shfl_xor(mx, 32));
        if (!__all(mx <= mX + 8.0f)) {      // defer-max (T13)
            const float mnew = fmaxf(mX, mx);
            const float sf = __builtin_amdgcn_exp2f(mX - mnew);
            mX = mnew;
            lX *= sf;
            float sfT[4];
#pragma unroll
            for (int r = 0; r < 4; r++) sfT[r] = __shfl(sf, 4 * lg + r);
#pragma unroll
            for (int j = 0; j < 4; j++) {
                o[j][0] *= sfT[0]; o[j][1] *= sfT[1];
                o[j][2] *= sfT[2]; o[j][3] *= sfT[3];
            }
        }
        float p0[4], p1[4];
#pragma unroll
        for (int r = 0; r < 4; r++) {
            p0[r] = __builtin_amdgcn_exp2f(s0[r] - mX);
            p1[r] = __builtin_amdgcn_exp2f(s1[r] - mX);
        }
        float sum = ((p0[0] + p0[1]) + (p0[2] + p0[3])) +
                    ((p1[0] + p1[1]) + (p1[2] + p1[3]));
        sum += __shfl_xor(sum, 16);
        sum += __shfl_xor(sum, 32);
        lX += sum;
        uint2 w0p = make_uint2(cvtpk(p0[0], p0[1]), cvtpk(p0[2], p0[3]));
        uint2 w1p = make_uint2(cvtpk(p1[0], p1[1]), cvtpk(p1[2], p1[3]));
        *reinterpret_cast<uint2*>(&P_lds[wid][l16][4 * lg]) = w0p;
        *reinterpret_cast<uint2*>(&P_lds[wid][l16][16 + 4 * lg]) = w1p;
        bf16x8 pf = *reinterpret_cast<const bf16x8*>(&P_lds[wid][l16][8 * lg]);
        __builtin_amdgcn_s_setprio(1);
        o[0] = __builtin_amdgcn_mfma_f32_16x16x32_bf16(pf, w0, o[0], 0, 0, 0);
        o[1] = __builtin_amdgcn_mfma_f32_16x16x32_bf16(pf, w1, o[1], 0, 0, 0);
        o[2] = __builtin_amdgcn_mfma_f32_16x16x32_bf16(pf, w2, o[2], 0, 0, 0);
        o[3] = __builtin_amdgcn_mfma_f32_16x16x32_bf16(pf, w3, o[3], 0, 0, 0);
        __builtin_amdgcn_s_setprio(0);
    };

    // K/V register double-buffers (named A/B, loop unrolled x2 — rule #20)
    bf16x8 kA0 = *reinterpret_cast<const bf16x8*>(&kb[l16 * 64 + 8 * lg]);
    bf16x8 kA1 = *reinterpret_cast<const bf16x8*>(&kb[l16 * 64 + 32 + 8 * lg]);
    bf16x8 kA2 = *reinterpret_cast<const bf16x8*>(&kb[(16 + l16) * 64 + 8 * lg]);
    bf16x8 kA3 = *reinterpret_cast<const bf16x8*>(&kb[(16 + l16) * 64 + 32 + 8 * lg]);
    bf16x8 vA0 = *reinterpret_cast<const bf16x8*>(&vb[l16 * 2048 + 8 * lg]);
    bf16x8 vA1 = *reinterpret_cast<const bf16x8*>(&vb[(16 + l16) * 2048 + 8 * lg]);
    bf16x8 vA2 = *reinterpret_cast<const bf16x8*>(&vb[(32 + l16) * 2048 + 8 * lg]);
    bf16x8 vA3 = *reinterpret_cast<const bf16x8*>(&vb[(48 + l16) * 2048 + 8 * lg]);

    int kv0 = 0;
    for (;;) {
        // ---- even step: process A, prefetch into B ----
        bool last = (kv0 + 32 >= kvEnd);
        bf16x8 kB0, kB1, kB2, kB3, vB0, vB1, vB2, vB3;
        if (!last) {
            const int kn = kv0 + 32;
            kB0 = *reinterpret_cast<const bf16x8*>(&kb[(kn + l16) * 64 + 8 * lg]);
            kB1 = *reinterpret_cast<const bf16x8*>(&kb[(kn + l16) * 64 + 32 + 8 * lg]);
            kB2 = *reinterpret_cast<const bf16x8*>(&kb[(kn + 16 + l16) * 64 + 8 * lg]);
            kB3 = *reinterpret_cast<const bf16x8*>(&kb[(kn + 16 + l16) * 64 + 32 + 8 * lg]);
            vB0 = *reinterpret_cast<const bf16x8*>(&vb[l16 * 2048 + kn + 8 * lg]);
            vB1 = *reinterpret_cast<const bf16x8*>(&vb[(16 + l16) * 2048 + kn + 8 * lg]);
            vB2 = *reinterpret_cast<const bf16x8*>(&vb[(32 + l16) * 2048 + kn + 8 * lg]);
            vB3 = *reinterpret_cast<const bf16x8*>(&vb[(48 + l16) * 2048 + kn + 8 * lg]);
        }
        process(kA0, kA1, kA2, kA3, vA0, vA1, vA2, vA3, kv0, last);
        kv0 += 32;
        if (last) break;
        // ---- odd step: process B, prefetch into A ----
        last = (kv0 + 32 >= kvEnd);
        if (!last) {
            const int kn = kv0 + 32;
            kA0 = *reinterpret_cast<const bf16x8*>(&kb[(kn + l16) * 64 + 8 * lg]);
            kA1 = *reinterpret_cast<const bf16x8*>(&kb[(kn + l16) * 64 + 32 + 8 * lg]);
            kA2 = *reinterpret_cast<const bf16x8*>(&kb[(kn + 16 + l16) * 64 + 8 * lg]);
            kA3 = *reinterpret_cast<const bf16x8*>(&kb[(kn + 16 + l16) * 64 + 32 + 8 * lg]);
            vA0 = *reinterpret_cast<const bf16x8*>(&vb[l16 * 2048 + kn + 8 * lg]);
            vA1 = *reinterpret_cast<const bf16x8*>(&vb[(16 + l16) * 2048 + kn + 8 * lg]);
            vA2 = *reinterpret_cast<const bf16x8*>(&vb[(32 + l16) * 2048 + kn + 8 * lg]);
            vA3 = *reinterpret_cast<const bf16x8*>(&vb[(48 + l16) * 2048 + kn + 8 * lg]);
        }
        process(kB0, kB1, kB2, kB3, vB0, vB1, vB2, vB3, kv0, last);
        kv0 += 32;
        if (last) break;
    }

    // epilogue
    const int b = bh >> 4, h = bh & 15;
    float inv[4];
#pragma unroll
    for (int r = 0; r < 4; r++) inv[r] = 1.0f / __shfl(lX, 4 * lg + r);
#pragma unroll
    for (int j = 0; j < 4; j++)
#pragma unroll
        for (int r = 0; r < 4; r++) {
            int n = q0 + 4 * lg + r;
            attn_out[(size_t)(b * 2048 + n) * 1024 + h * 64 + 16 * j + l16] =
                f2bf(o[j][r] * inv[r]);
        }
}

// ---- output projection: out = attn_out @ Wo^T (f32 out, no bias) ----
__global__ __launch_bounds__(256) void gemm_out_kernel(
    const unsigned short* __restrict__ abf, const unsigned short* __restrict__ wo,
    float* __restrict__ out) {
    __shared__ __align__(16) unsigned short As[128 * 32];
    __shared__ __align__(16) unsigned short Bs[64 * 32];
    const int m0 = blockIdx.y * 128;
    const int n0 = blockIdx.x * 64;
    f32x4 acc[4][2];
    gemm_core_128x64(abf, wo, m0, n0, 1024, As, Bs, acc);

    const int tid = threadIdx.x;
    const int lane = tid & 63;
    const int wid = tid >> 6;
    const int wr = wid >> 1, wc = wid & 1;
    const int l16 = lane & 15, lg = lane >> 4;
#pragma unroll
    for (int j = 0; j < 2; j++) {
        const int c = n0 + 32 * wc + 16 * j + l16;
#pragma unroll
        for (int i = 0; i < 4; i++) {
#pragma unroll
            for (int r = 0; r < 4; r++) {
                int m = m0 + 64 * wr + 16 * i + 4 * lg + r;
                out[(size_t)m * 1024 + c] = acc[i][j][r];
            }
        }
    }
}

extern "C" void kernel_launch(void* const* d_in, const int* in_sizes, int n_in,
                              void* d_out, int out_size, void* d_ws, size_t ws_size,
                              hipStream_t stream) {
    const float* x  = (const float*)d_in[0];
    const float* Wq = (const float*)d_in[1];
    const float* bq = (const float*)d_in[2];
    const float* Wk = (const float*)d_in[3];
    const float* bk = (const float*)d_in[4];
    const float* Wv = (const float*)d_in[5];
    const float* bv = (const float*)d_in[6];
    const float* Wo = (const float*)d_in[7];
    float* out = (float*)d_out;

    char* ws = (char*)d_ws;
    unsigned short* xbf  = (unsigned short*)(ws);
    unsigned short* wqbf = (unsigned short*)(ws + (8u  << 20));
    unsigned short* wkbf = (unsigned short*)(ws + (10u << 20));
    unsigned short* wvbf = (unsigned short*)(ws + (12u << 20));
    unsigned short* wobf = (unsigned short*)(ws + (14u << 20));
    unsigned short* qws  = (unsigned short*)(ws + (16u << 20));
    unsigned short* kws  = (unsigned short*)(ws + (24u << 20));
    unsigned short* vtws = (unsigned short*)(ws + (32u << 20));
    unsigned short* aows = (unsigned short*)(ws + (40u << 20));

    cast_bf16_kernel<<<4096, 256, 0, stream>>>(x, xbf, 4096 * 1024 / 4);
    cast_w4_kernel<<<dim3(1024, 4), 256, 0, stream>>>(
        Wq, Wk, Wv, Wo, wqbf, wkbf, wvbf, wobf);

    // QKV: 128x128 tiles -> (8, 32, 3) = 768 blocks (~3/CU, m97 structure)
    gemm_qkv_kernel<<<dim3(8, 32, 3), 256, 0, stream>>>(
        xbf, wqbf, wkbf, wvbf, bq, bk, bv, qws, kws, vtws);

    // attention: 1024 blocks x 4 waves = 4096 waves (16/CU)
    attn_kernel<<<1024, 256, 0, stream>>>(qws, kws, vtws, aows);

    // out projection: 128x64 tiles -> (16, 32) = 512 blocks (2/CU)
    gemm_out_kernel<<<dim3(16, 32), 256, 0, stream>>>(aows, wobf, out);
}

// Round 9
// 276.748 us; speedup vs baseline: 1.4492x; 1.4492x over previous
//
#include <hip/hip_runtime.h>
#include <hip/hip_bf16.h>

// Fused causal MHA for MI355X (gfx950).
// Round-8: paired attention (round-6 structure, the 120us version) + round-7's
// XCD-local bh mapping (FETCH 62.5->14.3 MB proven). No setprio (m190).
// Workspace (48 MB): [0,8M) x_bf16 | [8,16M) Wq/Wk/Wv/Wo bf16
//   [16,24M) Q (b,h,n,d) bf16 pre-scaled 0.125*log2e | [24,32M) K (b,h,n,d)
//   [32,40M) V^T (b,h,d,n) | [40,48M) attn_out (b,n,h*dv) bf16

using bf16x8   = __attribute__((ext_vector_type(8))) __bf16;
using f32x4    = __attribute__((ext_vector_type(4))) float;
using ushort4v = __attribute__((ext_vector_type(4))) unsigned short;

__device__ __forceinline__ unsigned short f2bf(float f) {
    unsigned int u = __float_as_uint(f);
    u += 0x7FFFu + ((u >> 16) & 1u);
    return (unsigned short)(u >> 16);
}

__device__ __forceinline__ unsigned cvtpk(float lo, float hi) {
    unsigned r;
    asm("v_cvt_pk_bf16_f32 %0, %1, %2" : "=v"(r) : "v"(lo), "v"(hi));
    return r;
}

__device__ __forceinline__ void gll16(const void* g, void* l) {
    __builtin_amdgcn_global_load_lds(
        (const __attribute__((address_space(1))) void*)g,
        (__attribute__((address_space(3))) void*)l, 16, 0, 0);
}

__global__ __launch_bounds__(256) void cast_bf16_kernel(
    const float* __restrict__ in, unsigned short* __restrict__ out, int n4) {
    int i = blockIdx.x * 256 + threadIdx.x;
    if (i >= n4) return;
    float4 f = reinterpret_cast<const float4*>(in)[i];
    ushort4v o;
    o.x = f2bf(f.x); o.y = f2bf(f.y); o.z = f2bf(f.z); o.w = f2bf(f.w);
    reinterpret_cast<ushort4v*>(out)[i] = o;
}

__global__ __launch_bounds__(256) void cast_w4_kernel(
    const float* __restrict__ w0, const float* __restrict__ w1,
    const float* __restrict__ w2, const float* __restrict__ w3,
    unsigned short* __restrict__ o0, unsigned short* __restrict__ o1,
    unsigned short* __restrict__ o2, unsigned short* __restrict__ o3) {
    const int z = blockIdx.y;
    const float* in = (z == 0) ? w0 : (z == 1) ? w1 : (z == 2) ? w2 : w3;
    unsigned short* out = (z == 0) ? o0 : (z == 1) ? o1 : (z == 2) ? o2 : o3;
    int i = blockIdx.x * 256 + threadIdx.x;
    float4 f = reinterpret_cast<const float4*>(in)[i];
    ushort4v o;
    o.x = f2bf(f.x); o.y = f2bf(f.y); o.z = f2bf(f.z); o.w = f2bf(f.w);
    reinterpret_cast<ushort4v*>(out)[i] = o;
}

// ---- 128x128 GEMM core (m97 structure): C = A(MxK) * B(NxK)^T ----
__device__ __forceinline__ void gemm_core_128(
    const unsigned short* __restrict__ A, const unsigned short* __restrict__ B,
    int m0, int n0, int K,
    unsigned short* As, unsigned short* Bs, f32x4 acc[4][4]) {
    const int tid = threadIdx.x;
    const int lane = tid & 63;
    const int wid = tid >> 6;
    const int wr = wid >> 1, wc = wid & 1;
    const int l16 = lane & 15, lg = lane >> 4;

#pragma unroll
    for (int i = 0; i < 4; i++)
#pragma unroll
        for (int j = 0; j < 4; j++) acc[i][j] = f32x4{0.f, 0.f, 0.f, 0.f};

    const int srow = lane >> 2;
    const int scol = (lane & 3) * 8;
    const unsigned short* Ab0 = &A[(size_t)(m0 + wid * 16 + srow) * K + scol];
    const unsigned short* Ab1 = &A[(size_t)(m0 + 64 + wid * 16 + srow) * K + scol];
    const unsigned short* Bb0 = &B[(size_t)(n0 + wid * 16 + srow) * K + scol];
    const unsigned short* Bb1 = &B[(size_t)(n0 + 64 + wid * 16 + srow) * K + scol];
    unsigned short* AsW0 = As + (wid * 16) * 32;
    unsigned short* AsW1 = As + (64 + wid * 16) * 32;
    unsigned short* BsW0 = Bs + (wid * 16) * 32;
    unsigned short* BsW1 = Bs + (64 + wid * 16) * 32;

    for (int k0 = 0; k0 < K; k0 += 32) {
        __syncthreads();
        gll16(Ab0 + k0, AsW0);
        gll16(Ab1 + k0, AsW1);
        gll16(Bb0 + k0, BsW0);
        gll16(Bb1 + k0, BsW1);
        __syncthreads();
        bf16x8 af[4], bfr[4];
#pragma unroll
        for (int i = 0; i < 4; i++)
            af[i] = *reinterpret_cast<const bf16x8*>(&As[(64 * wr + 16 * i + l16) * 32 + 8 * lg]);
#pragma unroll
        for (int j = 0; j < 4; j++)
            bfr[j] = *reinterpret_cast<const bf16x8*>(&Bs[(64 * wc + 16 * j + l16) * 32 + 8 * lg]);
#pragma unroll
        for (int i = 0; i < 4; i++)
#pragma unroll
            for (int j = 0; j < 4; j++)
                acc[i][j] = __builtin_amdgcn_mfma_f32_16x16x32_bf16(af[i], bfr[j], acc[i][j], 0, 0, 0);
    }
}

// ---- 128x64 GEMM core (out-proj) ----
__device__ __forceinline__ void gemm_core_128x64(
    const unsigned short* __restrict__ A, const unsigned short* __restrict__ B,
    int m0, int n0, int K,
    unsigned short* As, unsigned short* Bs, f32x4 acc[4][2]) {
    const int tid = threadIdx.x;
    const int lane = tid & 63;
    const int wid = tid >> 6;
    const int wr = wid >> 1, wc = wid & 1;
    const int l16 = lane & 15, lg = lane >> 4;

#pragma unroll
    for (int i = 0; i < 4; i++)
#pragma unroll
        for (int j = 0; j < 2; j++) acc[i][j] = f32x4{0.f, 0.f, 0.f, 0.f};

    const int srow = lane >> 2;
    const int scol = (lane & 3) * 8;
    const unsigned short* Ab0 = &A[(size_t)(m0 + wid * 16 + srow) * K + scol];
    const unsigned short* Ab1 = &A[(size_t)(m0 + 64 + wid * 16 + srow) * K + scol];
    const unsigned short* Bb0 = &B[(size_t)(n0 + wid * 16 + srow) * K + scol];
    unsigned short* AsW0 = As + (wid * 16) * 32;
    unsigned short* AsW1 = As + (64 + wid * 16) * 32;
    unsigned short* BsW0 = Bs + (wid * 16) * 32;

    for (int k0 = 0; k0 < K; k0 += 32) {
        __syncthreads();
        gll16(Ab0 + k0, AsW0);
        gll16(Ab1 + k0, AsW1);
        gll16(Bb0 + k0, BsW0);
        __syncthreads();
        bf16x8 af[4], bfr[2];
#pragma unroll
        for (int i = 0; i < 4; i++)
            af[i] = *reinterpret_cast<const bf16x8*>(&As[(64 * wr + 16 * i + l16) * 32 + 8 * lg]);
#pragma unroll
        for (int j = 0; j < 2; j++)
            bfr[j] = *reinterpret_cast<const bf16x8*>(&Bs[(32 * wc + 16 * j + l16) * 32 + 8 * lg]);
#pragma unroll
        for (int i = 0; i < 4; i++)
#pragma unroll
            for (int j = 0; j < 2; j++)
                acc[i][j] = __builtin_amdgcn_mfma_f32_16x16x32_bf16(af[i], bfr[j], acc[i][j], 0, 0, 0);
    }
}

// ---- QKV projection: z=0 -> Q (scaled 0.125*log2e), z=1 -> K, z=2 -> V^T ----
__global__ __launch_bounds__(256) void gemm_qkv_kernel(
    const unsigned short* __restrict__ xbf,
    const unsigned short* __restrict__ wq, const unsigned short* __restrict__ wk,
    const unsigned short* __restrict__ wv,
    const float* __restrict__ bq, const float* __restrict__ bk, const float* __restrict__ bv,
    unsigned short* __restrict__ q_ws, unsigned short* __restrict__ k_ws,
    unsigned short* __restrict__ vt_ws) {
    __shared__ __align__(16) unsigned short As[128 * 32];
    __shared__ __align__(16) unsigned short Bs[128 * 32];
    const int z = blockIdx.z;
    const unsigned short* W = (z == 0) ? wq : ((z == 1) ? wk : wv);
    const float* bias = (z == 0) ? bq : ((z == 1) ? bk : bv);
    const float scale = (z == 0) ? 0.125f * 1.44269504f : 1.0f;
    const int m0 = blockIdx.y * 128;
    const int n0 = blockIdx.x * 128;

    f32x4 acc[4][4];
    gemm_core_128(xbf, W, m0, n0, 1024, As, Bs, acc);

    const int tid = threadIdx.x;
    const int lane = tid & 63;
    const int wid = tid >> 6;
    const int wr = wid >> 1, wc = wid & 1;
    const int l16 = lane & 15, lg = lane >> 4;

#pragma unroll
    for (int j = 0; j < 4; j++) {
        const int c = n0 + 64 * wc + 16 * j + l16;
        const float bc = bias[c];
        const int h = c >> 6, d = c & 63;
#pragma unroll
        for (int i = 0; i < 4; i++) {
            const int mb = m0 + 64 * wr + 16 * i + 4 * lg;
            if (z < 2) {
                unsigned short* dst = (z == 0) ? q_ws : k_ws;
#pragma unroll
                for (int r = 0; r < 4; r++) {
                    int m = mb + r;
                    int b = m >> 11, n = m & 2047;
                    float v = (acc[i][j][r] + bc) * scale;
                    dst[(((b * 16 + h) * 2048 + n) << 6) + d] = f2bf(v);
                }
            } else {
                int b = mb >> 11, n = mb & 2047;
                ushort4v pk;
                pk.x = f2bf(acc[i][j][0] + bc);
                pk.y = f2bf(acc[i][j][1] + bc);
                pk.z = f2bf(acc[i][j][2] + bc);
                pk.w = f2bf(acc[i][j][3] + bc);
                *reinterpret_cast<ushort4v*>(&vt_ws[((b * 16 + h) * 64 + d) * 2048 + n]) = pk;
            }
        }
    }
}

// ---- Flash attention v5: paired q-tiles + XCD-local bh mapping ----
// bid 0..511: xcd = bid&7, idx = bid>>3 (0..63); bh = xcd*4 + (idx>>4);
// p = (idx&15)*4 + wid  -> q-tiles (p, 127-p). KV tiles of 32, K prefetch.
__global__ __launch_bounds__(256) void attn_kernel(
    const unsigned short* __restrict__ q_ws, const unsigned short* __restrict__ k_ws,
    const unsigned short* __restrict__ vt_ws, unsigned short* __restrict__ attn_out) {
    __shared__ __align__(16) unsigned short P_lds[4][2][16][40];   // wave, slot, q-row, k(+pad)
    const int tid = threadIdx.x;
    const int wid = tid >> 6, lane = tid & 63;
    const int l16 = lane & 15, lg = lane >> 4;
    const int bid = blockIdx.x;               // 0..511
    const int xcd = bid & 7, idx = bid >> 3;  // idx 0..63
    const int bh = xcd * 4 + (idx >> 4);      // 4 bh per XCD -> K/V L2-resident
    const int p = ((idx & 15) << 2) + wid;    // 0..63
    const int qA0 = p << 4;                   // 0..1008
    const int qB0 = 2032 - (p << 4);          // 2032..1024
    const unsigned short* qb = q_ws + bh * (2048 * 64);
    const unsigned short* kb = k_ws + bh * (2048 * 64);
    const unsigned short* vb = vt_ws + bh * (64 * 2048);

    // Q fragments (hoisted; pre-scaled). Operand layout [q=l16][d=8lg+j].
    bf16x8 aqA0 = *reinterpret_cast<const bf16x8*>(&qb[(qA0 + l16) * 64 + 8 * lg]);
    bf16x8 aqA1 = *reinterpret_cast<const bf16x8*>(&qb[(qA0 + l16) * 64 + 32 + 8 * lg]);
    bf16x8 aqB0 = *reinterpret_cast<const bf16x8*>(&qb[(qB0 + l16) * 64 + 8 * lg]);
    bf16x8 aqB1 = *reinterpret_cast<const bf16x8*>(&qb[(qB0 + l16) * 64 + 32 + 8 * lg]);

    f32x4 oA[4], oB[4];
#pragma unroll
    for (int j = 0; j < 4; j++) { oA[j] = f32x4{0.f, 0.f, 0.f, 0.f}; oB[j] = f32x4{0.f, 0.f, 0.f, 0.f}; }
    float mA = -1e30f, lA = 0.f, mB = -1e30f, lB = 0.f;

    // K prefetch for kv0 = 0
    bf16x8 k00 = *reinterpret_cast<const bf16x8*>(&kb[l16 * 64 + 8 * lg]);
    bf16x8 k01 = *reinterpret_cast<const bf16x8*>(&kb[l16 * 64 + 32 + 8 * lg]);
    bf16x8 k10 = *reinterpret_cast<const bf16x8*>(&kb[(16 + l16) * 64 + 8 * lg]);
    bf16x8 k11 = *reinterpret_cast<const bf16x8*>(&kb[(16 + l16) * 64 + 32 + 8 * lg]);

    const int kvEnd = qB0 + 16;
    for (int kv0 = 0; kv0 < kvEnd; kv0 += 32) {
        // V-tile loads (used after softmax); shared by A and B.
        bf16x8 v0 = *reinterpret_cast<const bf16x8*>(&vb[l16 * 2048 + kv0 + 8 * lg]);
        bf16x8 v1 = *reinterpret_cast<const bf16x8*>(&vb[(16 + l16) * 2048 + kv0 + 8 * lg]);
        bf16x8 v2 = *reinterpret_cast<const bf16x8*>(&vb[(32 + l16) * 2048 + kv0 + 8 * lg]);
        bf16x8 v3 = *reinterpret_cast<const bf16x8*>(&vb[(48 + l16) * 2048 + kv0 + 8 * lg]);

        const f32x4 z = f32x4{0.f, 0.f, 0.f, 0.f};
        // swapped QK^T: lane: q=l16, k=kv0 + {0,16} + 4lg + r
        f32x4 sB0 = __builtin_amdgcn_mfma_f32_16x16x32_bf16(k00, aqB0, z, 0, 0, 0);
        sB0 = __builtin_amdgcn_mfma_f32_16x16x32_bf16(k01, aqB1, sB0, 0, 0, 0);
        f32x4 sB1 = __builtin_amdgcn_mfma_f32_16x16x32_bf16(k10, aqB0, z, 0, 0, 0);
        sB1 = __builtin_amdgcn_mfma_f32_16x16x32_bf16(k11, aqB1, sB1, 0, 0, 0);
        const bool actA = kv0 < qA0 + 16;
        f32x4 sA0 = z, sA1 = z;
        if (actA) {
            sA0 = __builtin_amdgcn_mfma_f32_16x16x32_bf16(k00, aqA0, z, 0, 0, 0);
            sA0 = __builtin_amdgcn_mfma_f32_16x16x32_bf16(k01, aqA1, sA0, 0, 0, 0);
            sA1 = __builtin_amdgcn_mfma_f32_16x16x32_bf16(k10, aqA0, z, 0, 0, 0);
            sA1 = __builtin_amdgcn_mfma_f32_16x16x32_bf16(k11, aqA1, sA1, 0, 0, 0);
        }
        // prefetch next K tile
        if (kv0 + 32 < kvEnd) {
            const unsigned short* kr0 = &kb[(kv0 + 32 + l16) * 64 + 8 * lg];
            const unsigned short* kr1 = &kb[(kv0 + 48 + l16) * 64 + 8 * lg];
            k00 = *reinterpret_cast<const bf16x8*>(kr0);
            k01 = *reinterpret_cast<const bf16x8*>(kr0 + 32);
            k10 = *reinterpret_cast<const bf16x8*>(kr1);
            k11 = *reinterpret_cast<const bf16x8*>(kr1 + 32);
        }

        // softmax (log2 domain) + PV for one q-tile
        auto process = [&](f32x4 s0, f32x4 s1, int qX0, float& mX, float& lX,
                           f32x4* o, int slot, bool diag) {
            if (diag) {
                const int kbase = kv0 + 4 * lg;
                const int qrow = qX0 + l16;
#pragma unroll
                for (int r = 0; r < 4; r++) {
                    if (kbase + r > qrow) s0[r] = -1e30f;
                    if (kbase + 16 + r > qrow) s1[r] = -1e30f;
                }
            }
            float mx = fmaxf(fmaxf(fmaxf(s0[0], s0[1]), fmaxf(s0[2], s0[3])),
                             fmaxf(fmaxf(s1[0], s1[1]), fmaxf(s1[2], s1[3])));
            mx = fmaxf(mx, __shfl_xor(mx, 16));
            mx = fmaxf(mx, __shfl_xor(mx, 32));
            if (!__all(mx <= mX + 8.0f)) {      // defer-max (T13)
                const float mnew = fmaxf(mX, mx);
                const float sf = __builtin_amdgcn_exp2f(mX - mnew);
                mX = mnew;
                lX *= sf;
                float sfT[4];
#pragma unroll
                for (int r = 0; r < 4; r++) sfT[r] = __shfl(sf, 4 * lg + r);
#pragma unroll
                for (int j = 0; j < 4; j++) {
                    o[j][0] *= sfT[0]; o[j][1] *= sfT[1];
                    o[j][2] *= sfT[2]; o[j][3] *= sfT[3];
                }
            }
            float p0[4], p1[4];
#pragma unroll
            for (int r = 0; r < 4; r++) {
                p0[r] = __builtin_amdgcn_exp2f(s0[r] - mX);
                p1[r] = __builtin_amdgcn_exp2f(s1[r] - mX);
            }
            float sum = ((p0[0] + p0[1]) + (p0[2] + p0[3])) +
                        ((p1[0] + p1[1]) + (p1[2] + p1[3]));
            sum += __shfl_xor(sum, 16);
            sum += __shfl_xor(sum, 32);
            lX += sum;
            uint2 w0 = make_uint2(cvtpk(p0[0], p0[1]), cvtpk(p0[2], p0[3]));
            uint2 w1 = make_uint2(cvtpk(p1[0], p1[1]), cvtpk(p1[2], p1[3]));
            *reinterpret_cast<uint2*>(&P_lds[wid][slot][l16][4 * lg]) = w0;
            *reinterpret_cast<uint2*>(&P_lds[wid][slot][l16][16 + 4 * lg]) = w1;
            bf16x8 pf = *reinterpret_cast<const bf16x8*>(&P_lds[wid][slot][l16][8 * lg]);
            o[0] = __builtin_amdgcn_mfma_f32_16x16x32_bf16(pf, v0, o[0], 0, 0, 0);
            o[1] = __builtin_amdgcn_mfma_f32_16x16x32_bf16(pf, v1, o[1], 0, 0, 0);
            o[2] = __builtin_amdgcn_mfma_f32_16x16x32_bf16(pf, v2, o[2], 0, 0, 0);
            o[3] = __builtin_amdgcn_mfma_f32_16x16x32_bf16(pf, v3, o[3], 0, 0, 0);
        };
        const bool diagB = (kv0 + 32 >= kvEnd);
        process(sB0, sB1, qB0, mB, lB, oB, 1, diagB);
        if (actA) {
            const bool diagA = (kv0 + 32 >= qA0 + 16);
            process(sA0, sA1, qA0, mA, lA, oA, 0, diagA);
        }
    }

    // epilogue
    const int b = bh >> 4, h = bh & 15;
    auto epi = [&](int qX0, float lX, f32x4* o) {
        float inv[4];
#pragma unroll
        for (int r = 0; r < 4; r++) inv[r] = 1.0f / __shfl(lX, 4 * lg + r);
#pragma unroll
        for (int j = 0; j < 4; j++)
#pragma unroll
            for (int r = 0; r < 4; r++) {
                int n = qX0 + 4 * lg + r;
                attn_out[(size_t)(b * 2048 + n) * 1024 + h * 64 + 16 * j + l16] =
                    f2bf(o[j][r] * inv[r]);
            }
    };
    epi(qA0, lA, oA);
    epi(qB0, lB, oB);
}

// ---- output projection: out = attn_out @ Wo^T (f32 out, no bias) ----
__global__ __launch_bounds__(256) void gemm_out_kernel(
    const unsigned short* __restrict__ abf, const unsigned short* __restrict__ wo,
    float* __restrict__ out) {
    __shared__ __align__(16) unsigned short As[128 * 32];
    __shared__ __align__(16) unsigned short Bs[64 * 32];
    const int m0 = blockIdx.y * 128;
    const int n0 = blockIdx.x * 64;
    f32x4 acc[4][2];
    gemm_core_128x64(abf, wo, m0, n0, 1024, As, Bs, acc);

    const int tid = threadIdx.x;
    const int lane = tid & 63;
    const int wid = tid >> 6;
    const int wr = wid >> 1, wc = wid & 1;
    const int l16 = lane & 15, lg = lane >> 4;
#pragma unroll
    for (int j = 0; j < 2; j++) {
        const int c = n0 + 32 * wc + 16 * j + l16;
#pragma unroll
        for (int i = 0; i < 4; i++) {
#pragma unroll
            for (int r = 0; r < 4; r++) {
                int m = m0 + 64 * wr + 16 * i + 4 * lg + r;
                out[(size_t)m * 1024 + c] = acc[i][j][r];
            }
        }
    }
}

extern "C" void kernel_launch(void* const* d_in, const int* in_sizes, int n_in,
                              void* d_out, int out_size, void* d_ws, size_t ws_size,
                              hipStream_t stream) {
    const float* x  = (const float*)d_in[0];
    const float* Wq = (const float*)d_in[1];
    const float* bq = (const float*)d_in[2];
    const float* Wk = (const float*)d_in[3];
    const float* bk = (const float*)d_in[4];
    const float* Wv = (const float*)d_in[5];
    const float* bv = (const float*)d_in[6];
    const float* Wo = (const float*)d_in[7];
    float* out = (float*)d_out;

    char* ws = (char*)d_ws;
    unsigned short* xbf  = (unsigned short*)(ws);
    unsigned short* wqbf = (unsigned short*)(ws + (8u  << 20));
    unsigned short* wkbf = (unsigned short*)(ws + (10u << 20));
    unsigned short* wvbf = (unsigned short*)(ws + (12u << 20));
    unsigned short* wobf = (unsigned short*)(ws + (14u << 20));
    unsigned short* qws  = (unsigned short*)(ws + (16u << 20));
    unsigned short* kws  = (unsigned short*)(ws + (24u << 20));
    unsigned short* vtws = (unsigned short*)(ws + (32u << 20));
    unsigned short* aows = (unsigned short*)(ws + (40u << 20));

    cast_bf16_kernel<<<4096, 256, 0, stream>>>(x, xbf, 4096 * 1024 / 4);
    cast_w4_kernel<<<dim3(1024, 4), 256, 0, stream>>>(
        Wq, Wk, Wv, Wo, wqbf, wkbf, wvbf, wobf);

    // QKV: 128x128 tiles -> (8, 32, 3) = 768 blocks (~3/CU, m97 structure)
    gemm_qkv_kernel<<<dim3(8, 32, 3), 256, 0, stream>>>(
        xbf, wqbf, wkbf, wvbf, bq, bk, bv, qws, kws, vtws);

    // attention: 512 blocks x 4 waves, paired q-tiles, XCD-local bh
    attn_kernel<<<512, 256, 0, stream>>>(qws, kws, vtws, aows);

    // out projection: 128x64 tiles -> (16, 32) = 512 blocks (2/CU)
    gemm_out_kernel<<<dim3(16, 32), 256, 0, stream>>>(aows, wobf, out);
}